// Round 3
// 903.635 us; speedup vs baseline: 1.1471x; 1.1471x over previous
//
#include <hip/hip_runtime.h>
#include <stdint.h>

// ---------- types / helpers ----------
typedef __bf16 bf16x8 __attribute__((ext_vector_type(8)));
typedef float  f32x4  __attribute__((ext_vector_type(4)));

// convert 8 contiguous fp32 -> bf16x8 (RNE via clang __bf16 cast)
__device__ __forceinline__ bf16x8 cvt8(const float* __restrict__ p) {
    float4 lo = *(const float4*)p;
    float4 hi = *(const float4*)(p + 4);
    bf16x8 r;
    r[0] = (__bf16)lo.x; r[1] = (__bf16)lo.y; r[2] = (__bf16)lo.z; r[3] = (__bf16)lo.w;
    r[4] = (__bf16)hi.x; r[5] = (__bf16)hi.y; r[6] = (__bf16)hi.z; r[7] = (__bf16)hi.w;
    return r;
}

// pack 8 fp32 (two float4) -> bf16x8
__device__ __forceinline__ bf16x8 pack8(float4 lo, float4 hi) {
    bf16x8 r;
    r[0] = (__bf16)lo.x; r[1] = (__bf16)lo.y; r[2] = (__bf16)lo.z; r[3] = (__bf16)lo.w;
    r[4] = (__bf16)hi.x; r[5] = (__bf16)hi.y; r[6] = (__bf16)hi.z; r[7] = (__bf16)hi.w;
    return r;
}

// pair index for i<j over A=20 agents, lexicographic (matches np.unique of sorted pairs)
__device__ __forceinline__ int pidx(int i, int j) {
    return i * 19 - (i * (i - 1)) / 2 + (j - i - 1);
}

// ---------- GEMM (round-0 verbatim): C[M,N] = rowmap(X)[M,K] @ W[N,K]^T + bias
// MODE 0: glob  — X row r at offset r*81920        (x[:, :, 0, :], stride A*NIN)
// MODE 1: loc   — X row r at ((r/19)*20 + r%19 +1)*4096  (x[:, :, 1:, :])
// MODE 2: plain — X row r at r*K
// Tile: BM=64, BN=64, BK=32; 256 threads = 4 waves; wave w -> 32x32 quadrant.
template <int MODE, bool A_BF16, bool OUT_BF16>
__global__ __launch_bounds__(256) void gemm_bias_kernel(
    const void* __restrict__ Xv,
    const float* __restrict__ W,      // (N, K) fp32
    const float* __restrict__ bias,   // (N)    fp32
    void* __restrict__ Cv,
    int M, int N, int K)
{
    __shared__ __bf16 As[64][40];  // +8 pad keeps 16B alignment; 2-way bank alias is free
    __shared__ __bf16 Bs[64][40];

    const int tid  = threadIdx.x;
    const int srow = tid >> 2;          // 0..63 staging row
    const int scol = (tid & 3) << 3;    // 0,8,16,24 (elements)

    int gmrow = (int)blockIdx.y * 64 + srow;
    int rA = gmrow < M ? gmrow : M - 1;               // clamp; OOB rows never stored
    size_t aoff;
    if (MODE == 0)      aoff = (size_t)rA * 81920;
    else if (MODE == 1) aoff = ((size_t)(rA / 19) * 20 + (size_t)(rA % 19) + 1) * 4096;
    else                aoff = (size_t)rA * (size_t)K;
    const float*  aptrF = (const float*)Xv  + aoff + scol;   // used when !A_BF16
    const __bf16* aptrH = (const __bf16*)Xv + aoff + scol;   // used when  A_BF16
    const float*  bptr  = W + (size_t)((int)blockIdx.x * 64 + srow) * (size_t)K + scol;

    const int w    = tid >> 6;          // wave 0..3
    const int lane = tid & 63;
    const int wm   = (w >> 1) * 32;     // wave row offset in tile
    const int wn   = (w & 1) * 32;      // wave col offset in tile
    const int l    = lane & 15;
    const int qk   = lane >> 4;         // quad 0..3
    const int q8   = qk * 8;            // fragment k-offset (elements)

    f32x4 acc00 = {}, acc01 = {}, acc10 = {}, acc11 = {};

    for (int k0 = 0; k0 < K; k0 += 32) {
        bf16x8 av, bv;
        if (A_BF16) av = *(const bf16x8*)(aptrH + k0);
        else        av = cvt8(aptrF + k0);
        bv = cvt8(bptr + k0);
        __syncthreads();
        *(bf16x8*)&As[srow][scol] = av;
        *(bf16x8*)&Bs[srow][scol] = bv;
        __syncthreads();
        bf16x8 a0 = *(const bf16x8*)&As[wm + l][q8];
        bf16x8 a1 = *(const bf16x8*)&As[wm + 16 + l][q8];
        bf16x8 b0 = *(const bf16x8*)&Bs[wn + l][q8];
        bf16x8 b1 = *(const bf16x8*)&Bs[wn + 16 + l][q8];
        acc00 = __builtin_amdgcn_mfma_f32_16x16x32_bf16(a0, b0, acc00, 0, 0, 0);
        acc01 = __builtin_amdgcn_mfma_f32_16x16x32_bf16(a0, b1, acc01, 0, 0, 0);
        acc10 = __builtin_amdgcn_mfma_f32_16x16x32_bf16(a1, b0, acc10, 0, 0, 0);
        acc11 = __builtin_amdgcn_mfma_f32_16x16x32_bf16(a1, b1, acc11, 0, 0, 0);
    }

    // epilogue: C/D layout col=lane&15, row=(lane>>4)*4+reg
    const int colBase = (int)blockIdx.x * 64;
    const int rowBase = (int)blockIdx.y * 64;
    const float bias0 = bias[colBase + wn + l];
    const float bias1 = bias[colBase + wn + 16 + l];
    #pragma unroll
    for (int i = 0; i < 2; ++i) {
        f32x4 aj0 = (i == 0) ? acc00 : acc10;
        f32x4 aj1 = (i == 0) ? acc01 : acc11;
        #pragma unroll
        for (int r = 0; r < 4; ++r) {
            int row = rowBase + wm + i * 16 + qk * 4 + r;
            if (row < M) {
                size_t base = (size_t)row * (size_t)N + colBase + wn;
                float v0 = aj0[r] + bias0;
                float v1 = aj1[r] + bias1;
                if (OUT_BF16) {
                    ((__bf16*)Cv)[base + l]      = (__bf16)v0;
                    ((__bf16*)Cv)[base + 16 + l] = (__bf16)v1;
                } else {
                    ((float*)Cv)[base + l]      = v0;
                    ((float*)Cv)[base + 16 + l] = v1;
                }
            }
        }
    }
}

// ---------- loc GEMM v2 (bisect target): M=19000 N=512 K=4096, fp32 in/out
// 128x128 tile, BK=32, 4 waves each 64x64; double-buffered LDS, ONE barrier
// per K-step; next-step global loads issued right after the barrier.
// XCD-chunked bijective blockIdx swizzle (8 XCDs). Straight-line code.
__global__ __launch_bounds__(256) void gemm_loc_v2(
    const float* __restrict__ X,
    const float* __restrict__ W,      // (512, 4096)
    const float* __restrict__ bias,   // (512)
    float* __restrict__ C)            // (19000, 512)
{
    constexpr int M = 19000, N = 512, K = 4096;
    __shared__ __bf16 As[2][128][40];   // 20480 B
    __shared__ __bf16 Bs[2][128][40];   // 20480 B

    // bijective XCD-chunked swizzle; nwg = 4*149 = 596
    const int gx = 4, nwg = 596;
    int lid = (int)blockIdx.y * gx + (int)blockIdx.x;
    {
        int q = nwg >> 3, r = nwg & 7;          // q=74, r=4
        int xcd = lid & 7, idx = lid >> 3;
        lid = (xcd < r ? xcd * (q + 1) : r * (q + 1) + (xcd - r) * q) + idx;
    }
    const int tx = lid % gx;            // N-tile 0..3
    const int ty = lid / gx;            // M-tile 0..148

    const int tid  = threadIdx.x;
    const int srow = tid >> 2;          // 0..63
    const int scol = (tid & 3) << 3;    // 0,8,16,24

    int gr0 = ty * 128 + srow;      int rA0 = gr0 < M ? gr0 : M - 1;
    int gr1 = gr0 + 64;             int rA1 = gr1 < M ? gr1 : M - 1;
    const float* aptr0 = X + ((size_t)(rA0 / 19) * 20 + (size_t)(rA0 % 19) + 1) * 4096 + scol;
    const float* aptr1 = X + ((size_t)(rA1 / 19) * 20 + (size_t)(rA1 % 19) + 1) * 4096 + scol;
    const float* bptr0 = W + (size_t)(tx * 128 + srow) * (size_t)K + scol;
    const float* bptr1 = W + (size_t)(tx * 128 + 64 + srow) * (size_t)K + scol;

    const int w    = tid >> 6;
    const int lane = tid & 63;
    const int wm   = (w >> 1) * 64;
    const int wn   = (w & 1) * 64;
    const int l    = lane & 15;
    const int qk   = lane >> 4;
    const int q8   = qk << 3;

    f32x4 acc[4][4];
    #pragma unroll
    for (int m = 0; m < 4; ++m)
        #pragma unroll
        for (int n = 0; n < 4; ++n) { f32x4 z = {0.f, 0.f, 0.f, 0.f}; acc[m][n] = z; }

    float4 sa0l, sa0h, sa1l, sa1h, sb0l, sb0h, sb1l, sb1h;

    // prologue: load + write buf 0
    sa0l = *(const float4*)(aptr0);     sa0h = *(const float4*)(aptr0 + 4);
    sa1l = *(const float4*)(aptr1);     sa1h = *(const float4*)(aptr1 + 4);
    sb0l = *(const float4*)(bptr0);     sb0h = *(const float4*)(bptr0 + 4);
    sb1l = *(const float4*)(bptr1);     sb1h = *(const float4*)(bptr1 + 4);
    *(bf16x8*)&As[0][srow][scol]      = pack8(sa0l, sa0h);
    *(bf16x8*)&As[0][srow + 64][scol] = pack8(sa1l, sa1h);
    *(bf16x8*)&Bs[0][srow][scol]      = pack8(sb0l, sb0h);
    *(bf16x8*)&Bs[0][srow + 64][scol] = pack8(sb1l, sb1h);

    int cur = 0;
    for (int i = 0; i < K / 32; ++i) {
        __syncthreads();                         // buf[cur] ready; prior reads drained
        if (i + 1 < K / 32) {                    // issue next-step globals NOW
            int k0 = (i + 1) << 5;
            sa0l = *(const float4*)(aptr0 + k0); sa0h = *(const float4*)(aptr0 + k0 + 4);
            sa1l = *(const float4*)(aptr1 + k0); sa1h = *(const float4*)(aptr1 + k0 + 4);
            sb0l = *(const float4*)(bptr0 + k0); sb0h = *(const float4*)(bptr0 + k0 + 4);
            sb1l = *(const float4*)(bptr1 + k0); sb1h = *(const float4*)(bptr1 + k0 + 4);
        }
        bf16x8 af[4], bfr[4];
        #pragma unroll
        for (int m = 0; m < 4; ++m) af[m]  = *(const bf16x8*)&As[cur][wm + m * 16 + l][q8];
        #pragma unroll
        for (int n = 0; n < 4; ++n) bfr[n] = *(const bf16x8*)&Bs[cur][wn + n * 16 + l][q8];
        #pragma unroll
        for (int m = 0; m < 4; ++m)
            #pragma unroll
            for (int n = 0; n < 4; ++n)
                acc[m][n] = __builtin_amdgcn_mfma_f32_16x16x32_bf16(af[m], bfr[n], acc[m][n], 0, 0, 0);
        if (i + 1 < K / 32) {                    // vmcnt drain lands after MFMAs
            int nb = cur ^ 1;
            *(bf16x8*)&As[nb][srow][scol]      = pack8(sa0l, sa0h);
            *(bf16x8*)&As[nb][srow + 64][scol] = pack8(sa1l, sa1h);
            *(bf16x8*)&Bs[nb][srow][scol]      = pack8(sb0l, sb0h);
            *(bf16x8*)&Bs[nb][srow + 64][scol] = pack8(sb1l, sb1h);
        }
        cur ^= 1;
    }

    // epilogue: C/D layout col=lane&15, row=(lane>>4)*4+reg
    const int colBase = tx * 128 + wn;
    const int rowBase = ty * 128 + wm;
    float bs[4];
    #pragma unroll
    for (int n = 0; n < 4; ++n) bs[n] = bias[colBase + n * 16 + l];
    #pragma unroll
    for (int m = 0; m < 4; ++m) {
        #pragma unroll
        for (int r = 0; r < 4; ++r) {
            int row = rowBase + m * 16 + qk * 4 + r;
            if (row < M) {
                size_t base = (size_t)row * (size_t)N + colBase;
                #pragma unroll
                for (int n = 0; n < 4; ++n)
                    C[base + n * 16 + l] = acc[m][n][r] + bs[n];
            }
        }
    }
}

// ---------- phys stage 1: h1[g*190+p, c] = relu(concat(wcf[g,i],wcf[g,j]) . W1[c] + b1[c])
__global__ __launch_bounds__(256) void phys1_kernel(
    const float* __restrict__ wcf,   // (1000, 20*13) fp32
    const float* __restrict__ W1,    // (256, 26) fp32
    const float* __restrict__ b1,    // (256) fp32
    __bf16* __restrict__ h1)         // (1000*190, 256) bf16
{
    __shared__ float fs[260];
    const int g = blockIdx.x;
    const int c = threadIdx.x;
    for (int i = c; i < 260; i += 256) fs[i] = wcf[g * 260 + i];
    float wrow[26];
    #pragma unroll
    for (int k = 0; k < 26; ++k) wrow[k] = W1[c * 26 + k];
    const float bias = b1[c];
    __syncthreads();

    __bf16* out = h1 + (size_t)g * 190 * 256 + c;
    int p = 0;
    for (int i = 0; i < 20; ++i) {
        for (int j = i + 1; j < 20; ++j, ++p) {
            float s = bias;
            #pragma unroll
            for (int k = 0; k < 13; ++k) s += wrow[k]      * fs[i * 13 + k];
            #pragma unroll
            for (int k = 0; k < 13; ++k) s += wrow[13 + k] * fs[j * 13 + k];
            out[(size_t)p * 256] = (__bf16)(s > 0.f ? s : 0.f);
        }
    }
}

// ---------- segment max: agent[g,a,c] = max over 19 pairs containing a of phys[g,p,c]
__global__ __launch_bounds__(256) void segmax_kernel(
    const __bf16* __restrict__ phys,  // (1000*190, 256) bf16
    float* __restrict__ agent)        // (1000*20, 256) fp32
{
    const int a = blockIdx.x;   // 0..19
    const int g = blockIdx.y;   // 0..999
    const int c = threadIdx.x;
    const __bf16* base = phys + (size_t)g * 190 * 256 + c;
    float m = -3.4e38f;
    #pragma unroll
    for (int j = 0; j < 20; ++j) {
        if (j == a) continue;
        int p = (j > a) ? pidx(a, j) : pidx(j, a);
        float v = (float)base[(size_t)p * 256];
        m = v > m ? v : m;
    }
    agent[((size_t)g * 20 + a) * 256 + c] = m;
}

// ---------- launch ----------
extern "C" void kernel_launch(void* const* d_in, const int* in_sizes, int n_in,
                              void* d_out, int out_size, void* d_ws, size_t ws_size,
                              hipStream_t stream)
{
    const float* x   = (const float*)d_in[0];
    const float* wcf = (const float*)d_in[1];
    const float* Wg  = (const float*)d_in[2];
    const float* bg  = (const float*)d_in[3];
    const float* Wl  = (const float*)d_in[4];
    const float* bl  = (const float*)d_in[5];
    const float* W1  = (const float*)d_in[6];
    const float* b1  = (const float*)d_in[7];
    const float* W3  = (const float*)d_in[8];
    const float* b3  = (const float*)d_in[9];

    float* out   = (float*)d_out;
    float* glob  = out;                          // (1000, 1024)
    float* loc   = out + 1024000;                // (1000, 19, 512)
    float* agent = out + 1024000 + 9728000;      // (1000, 20, 256)

    __bf16* h1   = (__bf16*)d_ws;                    // (190000, 256) bf16
    __bf16* phys = h1 + (size_t)190000 * 256;        // (190000, 256) bf16

    // glob: M=1000 N=1024 K=4096  (fp32 in, fp32 out) — round-0 kernel
    gemm_bias_kernel<0, false, false><<<dim3(1024 / 64, (1000 + 63) / 64), 256, 0, stream>>>(
        x, Wg, bg, glob, 1000, 1024, 4096);
    // loc: M=19000 N=512 K=4096  (fp32 in, fp32 out) — NEW v2, 128x128 dbuf
    gemm_loc_v2<<<dim3(4, 149), 256, 0, stream>>>(x, Wl, bl, loc);
    // phys stage 1 (relu, K=26): fp32 in, bf16 out to ws
    phys1_kernel<<<1000, 256, 0, stream>>>(wcf, W1, b1, h1);
    // phys stage 2: M=190000 N=256 K=256 — round-0 kernel
    gemm_bias_kernel<2, true, true><<<dim3(256 / 64, (190000 + 63) / 64), 256, 0, stream>>>(
        h1, W3, b3, phys, 190000, 256, 256);
    // per-agent max over 19 pairs: bf16 in, fp32 out
    segmax_kernel<<<dim3(20, 1000), 256, 0, stream>>>(phys, agent);
}

// Round 5
// 898.967 us; speedup vs baseline: 1.1531x; 1.0052x over previous
//
#include <hip/hip_runtime.h>
#include <stdint.h>

// ---------- types / helpers ----------
typedef __bf16 bf16x8 __attribute__((ext_vector_type(8)));
typedef float  f32x4  __attribute__((ext_vector_type(4)));

// convert 8 contiguous fp32 -> bf16x8 (RNE via clang __bf16 cast)
__device__ __forceinline__ bf16x8 cvt8(const float* __restrict__ p) {
    float4 lo = *(const float4*)p;
    float4 hi = *(const float4*)(p + 4);
    bf16x8 r;
    r[0] = (__bf16)lo.x; r[1] = (__bf16)lo.y; r[2] = (__bf16)lo.z; r[3] = (__bf16)lo.w;
    r[4] = (__bf16)hi.x; r[5] = (__bf16)hi.y; r[6] = (__bf16)hi.z; r[7] = (__bf16)hi.w;
    return r;
}

// pack 8 fp32 (two float4) -> bf16x8
__device__ __forceinline__ bf16x8 pack8(float4 lo, float4 hi) {
    bf16x8 r;
    r[0] = (__bf16)lo.x; r[1] = (__bf16)lo.y; r[2] = (__bf16)lo.z; r[3] = (__bf16)lo.w;
    r[4] = (__bf16)hi.x; r[5] = (__bf16)hi.y; r[6] = (__bf16)hi.z; r[7] = (__bf16)hi.w;
    return r;
}

// pair index for i<j over A=20 agents, lexicographic (matches np.unique of sorted pairs)
__device__ __forceinline__ int pidx(int i, int j) {
    return i * 19 - (i * (i - 1)) / 2 + (j - i - 1);
}

// ---------- GEMM (round-0 verbatim, used for glob): 64x64 tile, 4 waves ----------
template <int MODE, bool A_BF16, bool OUT_BF16>
__global__ __launch_bounds__(256) void gemm_bias_kernel(
    const void* __restrict__ Xv,
    const float* __restrict__ W,      // (N, K) fp32
    const float* __restrict__ bias,   // (N)    fp32
    void* __restrict__ Cv,
    int M, int N, int K)
{
    __shared__ __bf16 As[64][40];
    __shared__ __bf16 Bs[64][40];

    const int tid  = threadIdx.x;
    const int srow = tid >> 2;
    const int scol = (tid & 3) << 3;

    int gmrow = (int)blockIdx.y * 64 + srow;
    int rA = gmrow < M ? gmrow : M - 1;
    size_t aoff;
    if (MODE == 0)      aoff = (size_t)rA * 81920;
    else if (MODE == 1) aoff = ((size_t)(rA / 19) * 20 + (size_t)(rA % 19) + 1) * 4096;
    else                aoff = (size_t)rA * (size_t)K;
    const float*  aptrF = (const float*)Xv  + aoff + scol;
    const __bf16* aptrH = (const __bf16*)Xv + aoff + scol;
    const float*  bptr  = W + (size_t)((int)blockIdx.x * 64 + srow) * (size_t)K + scol;

    const int w    = tid >> 6;
    const int lane = tid & 63;
    const int wm   = (w >> 1) * 32;
    const int wn   = (w & 1) * 32;
    const int l    = lane & 15;
    const int qk   = lane >> 4;
    const int q8   = qk * 8;

    f32x4 acc00 = {}, acc01 = {}, acc10 = {}, acc11 = {};

    for (int k0 = 0; k0 < K; k0 += 32) {
        bf16x8 av, bv;
        if (A_BF16) av = *(const bf16x8*)(aptrH + k0);
        else        av = cvt8(aptrF + k0);
        bv = cvt8(bptr + k0);
        __syncthreads();
        *(bf16x8*)&As[srow][scol] = av;
        *(bf16x8*)&Bs[srow][scol] = bv;
        __syncthreads();
        bf16x8 a0 = *(const bf16x8*)&As[wm + l][q8];
        bf16x8 a1 = *(const bf16x8*)&As[wm + 16 + l][q8];
        bf16x8 b0 = *(const bf16x8*)&Bs[wn + l][q8];
        bf16x8 b1 = *(const bf16x8*)&Bs[wn + 16 + l][q8];
        acc00 = __builtin_amdgcn_mfma_f32_16x16x32_bf16(a0, b0, acc00, 0, 0, 0);
        acc01 = __builtin_amdgcn_mfma_f32_16x16x32_bf16(a0, b1, acc01, 0, 0, 0);
        acc10 = __builtin_amdgcn_mfma_f32_16x16x32_bf16(a1, b0, acc10, 0, 0, 0);
        acc11 = __builtin_amdgcn_mfma_f32_16x16x32_bf16(a1, b1, acc11, 0, 0, 0);
    }

    const int colBase = (int)blockIdx.x * 64;
    const int rowBase = (int)blockIdx.y * 64;
    const float bias0 = bias[colBase + wn + l];
    const float bias1 = bias[colBase + wn + 16 + l];
    #pragma unroll
    for (int i = 0; i < 2; ++i) {
        f32x4 aj0 = (i == 0) ? acc00 : acc10;
        f32x4 aj1 = (i == 0) ? acc01 : acc11;
        #pragma unroll
        for (int r = 0; r < 4; ++r) {
            int row = rowBase + wm + i * 16 + qk * 4 + r;
            if (row < M) {
                size_t base = (size_t)row * (size_t)N + colBase + wn;
                float v0 = aj0[r] + bias0;
                float v1 = aj1[r] + bias1;
                if (OUT_BF16) {
                    ((__bf16*)Cv)[base + l]      = (__bf16)v0;
                    ((__bf16*)Cv)[base + 16 + l] = (__bf16)v1;
                } else {
                    ((float*)Cv)[base + l]      = v0;
                    ((float*)Cv)[base + 16 + l] = v1;
                }
            }
        }
    }
}

// ---------- loc GEMM, 8-wave variant of the round-3-passing gemm_loc_v2 ----------
// M=19000 N=512 K=4096, fp32 in/out. 128x128 tile, BK=32, 512 threads = 8 waves
// (2x4), each wave a 64x32 output block (MR=4, NR=2). Same dbuf/1-barrier/
// next-step-prefetch structure that passed in round 3; only the thread/wave
// geometry changed (1 staging row per thread instead of 2).
__global__ __launch_bounds__(512) void gemm_loc_w8(
    const float* __restrict__ X,
    const float* __restrict__ W,      // (512, 4096)
    const float* __restrict__ bias,   // (512)
    float* __restrict__ C)            // (19000, 512)
{
    constexpr int M = 19000, N = 512, K = 4096;
    __shared__ __bf16 As[2][128][40];   // 20480 B
    __shared__ __bf16 Bs[2][128][40];   // 20480 B

    // bijective XCD-chunked swizzle; nwg = 4*149 = 596
    const int gx = 4, nwg = 596;
    int lid = (int)blockIdx.y * gx + (int)blockIdx.x;
    {
        int q = nwg >> 3, r = nwg & 7;          // q=74, r=4
        int xcd = lid & 7, idx = lid >> 3;
        lid = (xcd < r ? xcd * (q + 1) : r * (q + 1) + (xcd - r) * q) + idx;
    }
    const int tx = lid % gx;            // N-tile 0..3
    const int ty = lid / gx;            // M-tile 0..148

    const int tid  = threadIdx.x;
    const int srow = tid >> 2;          // 0..127
    const int scol = (tid & 3) << 3;    // 0,8,16,24

    int gr = ty * 128 + srow;
    int rA = gr < M ? gr : M - 1;
    const float* aptr = X + ((size_t)(rA / 19) * 20 + (size_t)(rA % 19) + 1) * 4096 + scol;
    const float* bptr = W + (size_t)(tx * 128 + srow) * (size_t)K + scol;

    const int w    = tid >> 6;          // 0..7
    const int lane = tid & 63;
    const int wm   = (w >> 2) * 64;     // 0 or 64
    const int wn   = (w & 3) * 32;      // 0,32,64,96
    const int l    = lane & 15;
    const int qk   = lane >> 4;
    const int q8   = qk << 3;

    f32x4 acc[4][2];
    #pragma unroll
    for (int m = 0; m < 4; ++m)
        #pragma unroll
        for (int n = 0; n < 2; ++n) { f32x4 z = {0.f, 0.f, 0.f, 0.f}; acc[m][n] = z; }

    float4 sal, sah, sbl, sbh;

    // prologue: load + write buf 0
    sal = *(const float4*)(aptr);     sah = *(const float4*)(aptr + 4);
    sbl = *(const float4*)(bptr);     sbh = *(const float4*)(bptr + 4);
    *(bf16x8*)&As[0][srow][scol] = pack8(sal, sah);
    *(bf16x8*)&Bs[0][srow][scol] = pack8(sbl, sbh);

    int cur = 0;
    for (int i = 0; i < K / 32; ++i) {
        __syncthreads();                         // buf[cur] ready; prior reads drained
        if (i + 1 < K / 32) {                    // issue next-step globals NOW
            int k0 = (i + 1) << 5;
            sal = *(const float4*)(aptr + k0); sah = *(const float4*)(aptr + k0 + 4);
            sbl = *(const float4*)(bptr + k0); sbh = *(const float4*)(bptr + k0 + 4);
        }
        bf16x8 af[4], bfr[2];
        #pragma unroll
        for (int m = 0; m < 4; ++m) af[m]  = *(const bf16x8*)&As[cur][wm + m * 16 + l][q8];
        #pragma unroll
        for (int n = 0; n < 2; ++n) bfr[n] = *(const bf16x8*)&Bs[cur][wn + n * 16 + l][q8];
        #pragma unroll
        for (int m = 0; m < 4; ++m)
            #pragma unroll
            for (int n = 0; n < 2; ++n)
                acc[m][n] = __builtin_amdgcn_mfma_f32_16x16x32_bf16(af[m], bfr[n], acc[m][n], 0, 0, 0);
        if (i + 1 < K / 32) {                    // vmcnt drain lands after MFMAs
            int nb = cur ^ 1;
            *(bf16x8*)&As[nb][srow][scol] = pack8(sal, sah);
            *(bf16x8*)&Bs[nb][srow][scol] = pack8(sbl, sbh);
        }
        cur ^= 1;
    }

    // epilogue: C/D layout col=lane&15, row=(lane>>4)*4+reg
    const int colBase = tx * 128 + wn;
    const int rowBase = ty * 128 + wm;
    float bs[2];
    #pragma unroll
    for (int n = 0; n < 2; ++n) bs[n] = bias[colBase + n * 16 + l];
    #pragma unroll
    for (int m = 0; m < 4; ++m) {
        #pragma unroll
        for (int r = 0; r < 4; ++r) {
            int row = rowBase + m * 16 + qk * 4 + r;
            if (row < M) {
                size_t base = (size_t)row * (size_t)N + colBase;
                #pragma unroll
                for (int n = 0; n < 2; ++n)
                    C[base + n * 16 + l] = acc[m][n][r] + bs[n];
            }
        }
    }
}

// ---------- phys2 GEMM, same 8-wave structure: M=190000 N=256 K=256 ----------
// bf16 A (h1 in ws), fp32 W3 (converted), bf16 out. Near-verbatim copy of
// gemm_loc_w8 with MODE-2 addressing and bf16 A loads.
__global__ __launch_bounds__(512) void gemm_phys2_w8(
    const __bf16* __restrict__ Xh,    // (190000, 256) bf16
    const float* __restrict__ W,      // (256, 256) fp32
    const float* __restrict__ bias,   // (256)
    __bf16* __restrict__ C)           // (190000, 256) bf16
{
    constexpr int M = 190000, N = 256, K = 256;
    __shared__ __bf16 As[2][128][40];
    __shared__ __bf16 Bs[2][128][40];

    // bijective XCD-chunked swizzle; nwg = 2*1485 = 2970
    const int gx = 2, nwg = 2970;
    int lid = (int)blockIdx.y * gx + (int)blockIdx.x;
    {
        int q = nwg >> 3, r = nwg & 7;          // q=371, r=2
        int xcd = lid & 7, idx = lid >> 3;
        lid = (xcd < r ? xcd * (q + 1) : r * (q + 1) + (xcd - r) * q) + idx;
    }
    const int tx = lid % gx;            // N-tile 0..1
    const int ty = lid / gx;            // M-tile 0..1484

    const int tid  = threadIdx.x;
    const int srow = tid >> 2;          // 0..127
    const int scol = (tid & 3) << 3;    // 0,8,16,24

    int gr = ty * 128 + srow;
    int rA = gr < M ? gr : M - 1;
    const __bf16* aptr = Xh + (size_t)rA * (size_t)K + scol;
    const float*  bptr = W + (size_t)(tx * 128 + srow) * (size_t)K + scol;

    const int w    = tid >> 6;
    const int lane = tid & 63;
    const int wm   = (w >> 2) * 64;
    const int wn   = (w & 3) * 32;
    const int l    = lane & 15;
    const int qk   = lane >> 4;
    const int q8   = qk << 3;

    f32x4 acc[4][2];
    #pragma unroll
    for (int m = 0; m < 4; ++m)
        #pragma unroll
        for (int n = 0; n < 2; ++n) { f32x4 z = {0.f, 0.f, 0.f, 0.f}; acc[m][n] = z; }

    bf16x8 sav;
    float4 sbl, sbh;

    sav = *(const bf16x8*)(aptr);
    sbl = *(const float4*)(bptr);     sbh = *(const float4*)(bptr + 4);
    *(bf16x8*)&As[0][srow][scol] = sav;
    *(bf16x8*)&Bs[0][srow][scol] = pack8(sbl, sbh);

    int cur = 0;
    for (int i = 0; i < K / 32; ++i) {
        __syncthreads();
        if (i + 1 < K / 32) {
            int k0 = (i + 1) << 5;
            sav = *(const bf16x8*)(aptr + k0);
            sbl = *(const float4*)(bptr + k0); sbh = *(const float4*)(bptr + k0 + 4);
        }
        bf16x8 af[4], bfr[2];
        #pragma unroll
        for (int m = 0; m < 4; ++m) af[m]  = *(const bf16x8*)&As[cur][wm + m * 16 + l][q8];
        #pragma unroll
        for (int n = 0; n < 2; ++n) bfr[n] = *(const bf16x8*)&Bs[cur][wn + n * 16 + l][q8];
        #pragma unroll
        for (int m = 0; m < 4; ++m)
            #pragma unroll
            for (int n = 0; n < 2; ++n)
                acc[m][n] = __builtin_amdgcn_mfma_f32_16x16x32_bf16(af[m], bfr[n], acc[m][n], 0, 0, 0);
        if (i + 1 < K / 32) {
            int nb = cur ^ 1;
            *(bf16x8*)&As[nb][srow][scol] = sav;
            *(bf16x8*)&Bs[nb][srow][scol] = pack8(sbl, sbh);
        }
        cur ^= 1;
    }

    const int colBase = tx * 128 + wn;
    const int rowBase = ty * 128 + wm;
    float bs[2];
    #pragma unroll
    for (int n = 0; n < 2; ++n) bs[n] = bias[colBase + n * 16 + l];
    #pragma unroll
    for (int m = 0; m < 4; ++m) {
        #pragma unroll
        for (int r = 0; r < 4; ++r) {
            int row = rowBase + m * 16 + qk * 4 + r;
            if (row < M) {
                size_t base = (size_t)row * (size_t)N + colBase;
                #pragma unroll
                for (int n = 0; n < 2; ++n)
                    C[base + n * 16 + l] = (__bf16)(acc[m][n][r] + bs[n]);
            }
        }
    }
}

// ---------- phys stage 1: h1[g*190+p, c] = relu(concat(wcf[g,i],wcf[g,j]) . W1[c] + b1[c])
__global__ __launch_bounds__(256) void phys1_kernel(
    const float* __restrict__ wcf,   // (1000, 20*13) fp32
    const float* __restrict__ W1,    // (256, 26) fp32
    const float* __restrict__ b1,    // (256) fp32
    __bf16* __restrict__ h1)         // (1000*190, 256) bf16
{
    __shared__ float fs[260];
    const int g = blockIdx.x;
    const int c = threadIdx.x;
    for (int i = c; i < 260; i += 256) fs[i] = wcf[g * 260 + i];
    float wrow[26];
    #pragma unroll
    for (int k = 0; k < 26; ++k) wrow[k] = W1[c * 26 + k];
    const float bias = b1[c];
    __syncthreads();

    __bf16* out = h1 + (size_t)g * 190 * 256 + c;
    int p = 0;
    for (int i = 0; i < 20; ++i) {
        for (int j = i + 1; j < 20; ++j, ++p) {
            float s = bias;
            #pragma unroll
            for (int k = 0; k < 13; ++k) s += wrow[k]      * fs[i * 13 + k];
            #pragma unroll
            for (int k = 0; k < 13; ++k) s += wrow[13 + k] * fs[j * 13 + k];
            out[(size_t)p * 256] = (__bf16)(s > 0.f ? s : 0.f);
        }
    }
}

// ---------- segment max: agent[g,a,c] = max over 19 pairs containing a of phys[g,p,c]
__global__ __launch_bounds__(256) void segmax_kernel(
    const __bf16* __restrict__ phys,  // (1000*190, 256) bf16
    float* __restrict__ agent)        // (1000*20, 256) fp32
{
    const int a = blockIdx.x;   // 0..19
    const int g = blockIdx.y;   // 0..999
    const int c = threadIdx.x;
    const __bf16* base = phys + (size_t)g * 190 * 256 + c;
    float m = -3.4e38f;
    #pragma unroll
    for (int j = 0; j < 20; ++j) {
        if (j == a) continue;
        int p = (j > a) ? pidx(a, j) : pidx(j, a);
        float v = (float)base[(size_t)p * 256];
        m = v > m ? v : m;
    }
    agent[((size_t)g * 20 + a) * 256 + c] = m;
}

// ---------- launch ----------
extern "C" void kernel_launch(void* const* d_in, const int* in_sizes, int n_in,
                              void* d_out, int out_size, void* d_ws, size_t ws_size,
                              hipStream_t stream)
{
    const float* x   = (const float*)d_in[0];
    const float* wcf = (const float*)d_in[1];
    const float* Wg  = (const float*)d_in[2];
    const float* bg  = (const float*)d_in[3];
    const float* Wl  = (const float*)d_in[4];
    const float* bl  = (const float*)d_in[5];
    const float* W1  = (const float*)d_in[6];
    const float* b1  = (const float*)d_in[7];
    const float* W3  = (const float*)d_in[8];
    const float* b3  = (const float*)d_in[9];

    float* out   = (float*)d_out;
    float* glob  = out;                          // (1000, 1024)
    float* loc   = out + 1024000;                // (1000, 19, 512)
    float* agent = out + 1024000 + 9728000;      // (1000, 20, 256)

    __bf16* h1   = (__bf16*)d_ws;                    // (190000, 256) bf16
    __bf16* phys = h1 + (size_t)190000 * 256;        // (190000, 256) bf16

    // glob: M=1000 N=1024 K=4096 — round-0 kernel (passed twice)
    gemm_bias_kernel<0, false, false><<<dim3(1024 / 64, (1000 + 63) / 64), 256, 0, stream>>>(
        x, Wg, bg, glob, 1000, 1024, 4096);
    // loc: M=19000 N=512 K=4096 — 8-wave 128x128 dbuf (occupancy fix)
    gemm_loc_w8<<<dim3(4, 149), 512, 0, stream>>>(x, Wl, bl, loc);
    // phys stage 1 (relu, K=26): fp32 in, bf16 out to ws
    phys1_kernel<<<1000, 256, 0, stream>>>(wcf, W1, b1, h1);
    // phys stage 2: M=190000 N=256 K=256 — 8-wave 128x128 dbuf
    gemm_phys2_w8<<<dim3(2, 1485), 512, 0, stream>>>(h1, W3, b3, phys);
    // per-agent max over 19 pairs: bf16 in, fp32 out
    segmax_kernel<<<dim3(20, 1000), 256, 0, stream>>>(phys, agent);
}